// Round 7
// baseline (50.094 us; speedup 1.0000x reference)
//
#include <hip/hip_runtime.h>
#include <hip/hip_bf16.h>

// Problem constants: features [16, 512, 56, 56] f32, k=3 -> d=1
#define BB 16
#define CC 512
#define HH 56
#define WW 56
#define HW (HH * WW)
#define NPIX (BB * HW)   // 50176 output pixels
#define CGROUPS 8

__device__ __forceinline__ float shfl64(float v, int srcLane) {
    return __shfl(v, srcLane, 64);
}

// Proven math (rounds 1/2/5/6, absmax <= 2e-3 < 9e-3); masks & 1/9 cancel:
//   V  = mym*g(y-1) + g(y) + myp*g(y+1)
//   w3 = mym*g(y)   + g(cl(y+1)) + myp*g(cl(y+2))
//   w4 = mym*g(cl(y-2)) + g(cl(y-1)) + myp*g(y)
//   f1(x) = mxm*V(cl(x-2)) + V(cl(x-1)) + mxp*V(x)
//   f2(x) = mxm*V(x) + V(cl(x+1)) + mxp*V(cl(x+2))
//   f3(x) = mxm*w3(cl(x-1)) + w3(x) + mxp*w3(cl(x+1))
//   f4(x) = mxm*w4(cl(x-1)) + w4(x) + mxp*w4(cl(x+1))
// Wave = one row y. lane = sc*16 + q: sc = channel sub-group (4 channels per
// wave-iter), q = x-quad (float4/thread, q<14 active). 8 bpermutes per iter
// serve 4 channels. 2-stage pipeline with sched_barrier pins + launch_bounds
// (256,5) so the compiler cannot sink the prefetch (R1/R6 sank it at 40 VGPR).
// Epilogue: xor16+xor32 reduce across sc, coalesced float4 slab stores.
template <int NITER, bool WRITE_OUT>
__global__ __launch_bounds__(256, 5) void ComputeTotalSim_84267258347855_kernel(
    const float* __restrict__ feat, float* __restrict__ ws, float* __restrict__ out) {
    const int wave = threadIdx.x >> 6;
    const int lane = threadIdx.x & 63;
    const int sc = lane >> 4;
    const int q = lane & 15;
    const int qs = (q <= 13) ? q : 13;  // idle lanes load safe real data
    const int x0 = 4 * qs;
    const int b = blockIdx.z;
    const int cg = blockIdx.x;
    const int y = blockIdx.y * 4 + wave;

    const float mym = (y >= 1) ? 1.f : 0.f;
    const float myp = (y <= HH - 2) ? 1.f : 0.f;
    const float mxm[4] = {(q == 0) ? 0.f : 1.f, 1.f, 1.f, 1.f};   // x>=1
    const float mxp[4] = {1.f, 1.f, 1.f, (q >= 13) ? 0.f : 1.f};  // x<=54

    const int ry0 = (y - 2 < 0) ? 0 : y - 2;
    const int ry1 = (y - 1 < 0) ? 0 : y - 1;
    const int ry3 = (y + 1 > HH - 1) ? HH - 1 : y + 1;
    const int ry4 = (y + 2 > HH - 1) ? HH - 1 : y + 2;
    const int o0 = ry0 * WW + x0, o1 = ry1 * WW + x0, o2 = y * WW + x0,
              o3 = ry3 * WW + x0, o4 = ry4 * WW + x0;

    // channels: cg*(4*NITER) + 4*k + sc, k = 0..NITER-1
    const float* p = feat + ((size_t)b * CC + (size_t)cg * (4 * NITER) + sc) * HW;

    float s12h[4] = {0, 0, 0, 0}, s11[4] = {0, 0, 0, 0}, s22[4] = {0, 0, 0, 0};
    float s12v[4] = {0, 0, 0, 0}, s33[4] = {0, 0, 0, 0}, s44[4] = {0, 0, 0, 0};

#define STEP(A0, A1, A2, A3, A4)                                                 \
    {                                                                            \
        float4 V, w3, w4;                                                        \
        V.x = fmaf(mym, A1.x, fmaf(myp, A3.x, A2.x));                            \
        V.y = fmaf(mym, A1.y, fmaf(myp, A3.y, A2.y));                            \
        V.z = fmaf(mym, A1.z, fmaf(myp, A3.z, A2.z));                            \
        V.w = fmaf(mym, A1.w, fmaf(myp, A3.w, A2.w));                            \
        w3.x = fmaf(mym, A2.x, fmaf(myp, A4.x, A3.x));                           \
        w3.y = fmaf(mym, A2.y, fmaf(myp, A4.y, A3.y));                           \
        w3.z = fmaf(mym, A2.z, fmaf(myp, A4.z, A3.z));                           \
        w3.w = fmaf(mym, A2.w, fmaf(myp, A4.w, A3.w));                           \
        w4.x = fmaf(mym, A0.x, fmaf(myp, A2.x, A1.x));                           \
        w4.y = fmaf(mym, A0.y, fmaf(myp, A2.y, A1.y));                           \
        w4.z = fmaf(mym, A0.z, fmaf(myp, A2.z, A1.z));                           \
        w4.w = fmaf(mym, A0.w, fmaf(myp, A2.w, A1.w));                           \
        float Vm2 = shfl64(V.z, lane - 1), Vm1 = shfl64(V.w, lane - 1);          \
        float Vp4 = shfl64(V.x, lane + 1), Vp5 = shfl64(V.y, lane + 1);          \
        float w3m = shfl64(w3.w, lane - 1), w3p = shfl64(w3.x, lane + 1);        \
        float w4m = shfl64(w4.w, lane - 1), w4p = shfl64(w4.x, lane + 1);        \
        if (q == 0) { Vm2 = V.x; Vm1 = V.x; w3m = w3.x; w4m = w4.x; }            \
        if (q >= 13) { Vp4 = V.w; Vp5 = V.w; w3p = w3.w; w4p = w4.w; }           \
        const float Ve[8] = {Vm2, Vm1, V.x, V.y, V.z, V.w, Vp4, Vp5};            \
        const float W3a[6] = {w3m, w3.x, w3.y, w3.z, w3.w, w3p};                 \
        const float W4a[6] = {w4m, w4.x, w4.y, w4.z, w4.w, w4p};                 \
        _Pragma("unroll")                                                        \
        for (int j = 0; j < 4; ++j) {                                            \
            const float f1 = fmaf(mxm[j], Ve[j], fmaf(mxp[j], Ve[j+2], Ve[j+1]));    \
            const float f2 = fmaf(mxm[j], Ve[j+2], fmaf(mxp[j], Ve[j+4], Ve[j+3]));  \
            const float f3 = fmaf(mxm[j], W3a[j], fmaf(mxp[j], W3a[j+2], W3a[j+1])); \
            const float f4 = fmaf(mxm[j], W4a[j], fmaf(mxp[j], W4a[j+2], W4a[j+1])); \
            s12h[j] = fmaf(f1, f2, s12h[j]);                                     \
            s11[j]  = fmaf(f1, f1, s11[j]);                                      \
            s22[j]  = fmaf(f2, f2, s22[j]);                                      \
            s12v[j] = fmaf(f3, f4, s12v[j]);                                     \
            s33[j]  = fmaf(f3, f3, s33[j]);                                      \
            s44[j]  = fmaf(f4, f4, s44[j]);                                      \
        }                                                                        \
    }

    // ---- 2-stage software pipeline over channel quads (stride 4 channels) ----
    float4 A0 = *(const float4*)(p + o0), A1 = *(const float4*)(p + o1),
           A2 = *(const float4*)(p + o2), A3 = *(const float4*)(p + o3),
           A4 = *(const float4*)(p + o4);
    p += 4 * HW;
    for (int k = 0; k + 2 <= NITER; k += 2) {
        const float4 B0 = *(const float4*)(p + o0), B1 = *(const float4*)(p + o1),
                     B2 = *(const float4*)(p + o2), B3 = *(const float4*)(p + o3),
                     B4 = *(const float4*)(p + o4);
        __builtin_amdgcn_sched_barrier(0);  // loads must issue before STEP(A)
        STEP(A0, A1, A2, A3, A4);
        const float* pn = (k + 2 < NITER) ? p + 4 * HW : p;  // last pair: dummy re-read
        A0 = *(const float4*)(pn + o0); A1 = *(const float4*)(pn + o1);
        A2 = *(const float4*)(pn + o2); A3 = *(const float4*)(pn + o3);
        A4 = *(const float4*)(pn + o4);
        __builtin_amdgcn_sched_barrier(0);  // loads must issue before STEP(B)
        STEP(B0, B1, B2, B3, B4);
        p = pn + 4 * HW;
    }
#undef STEP

    // ---- reduce across the 4 channel sub-groups (lanes q, q+16, q+32, q+48) ----
#pragma unroll
    for (int j = 0; j < 4; ++j) {
        s12h[j] += __shfl_xor(s12h[j], 16, 64); s12h[j] += __shfl_xor(s12h[j], 32, 64);
        s11[j]  += __shfl_xor(s11[j], 16, 64);  s11[j]  += __shfl_xor(s11[j], 32, 64);
        s22[j]  += __shfl_xor(s22[j], 16, 64);  s22[j]  += __shfl_xor(s22[j], 32, 64);
        s12v[j] += __shfl_xor(s12v[j], 16, 64); s12v[j] += __shfl_xor(s12v[j], 32, 64);
        s33[j]  += __shfl_xor(s33[j], 16, 64);  s33[j]  += __shfl_xor(s33[j], 32, 64);
        s44[j]  += __shfl_xor(s44[j], 16, 64);  s44[j]  += __shfl_xor(s44[j], 32, 64);
    }

    if (lane < 14) {  // sc==0, q<14
        const int pix = b * HW + y * WW + 4 * q;
        if (WRITE_OUT) {
            float4 r;
            r.x = (float)(0.5 * ((double)s12h[0] / sqrt((double)s11[0] * (double)s22[0]) +
                                 (double)s12v[0] / sqrt((double)s33[0] * (double)s44[0])));
            r.y = (float)(0.5 * ((double)s12h[1] / sqrt((double)s11[1] * (double)s22[1]) +
                                 (double)s12v[1] / sqrt((double)s33[1] * (double)s44[1])));
            r.z = (float)(0.5 * ((double)s12h[2] / sqrt((double)s11[2] * (double)s22[2]) +
                                 (double)s12v[2] / sqrt((double)s33[2] * (double)s44[2])));
            r.w = (float)(0.5 * ((double)s12h[3] / sqrt((double)s11[3] * (double)s22[3]) +
                                 (double)s12v[3] / sqrt((double)s33[3] * (double)s44[3])));
            *(float4*)(out + pix) = r;
        } else {
            float* slab = ws + (size_t)cg * 6 * NPIX;
            *(float4*)(slab + 0 * NPIX + pix) = make_float4(s12h[0], s12h[1], s12h[2], s12h[3]);
            *(float4*)(slab + 1 * NPIX + pix) = make_float4(s11[0], s11[1], s11[2], s11[3]);
            *(float4*)(slab + 2 * NPIX + pix) = make_float4(s22[0], s22[1], s22[2], s22[3]);
            *(float4*)(slab + 3 * NPIX + pix) = make_float4(s12v[0], s12v[1], s12v[2], s12v[3]);
            *(float4*)(slab + 4 * NPIX + pix) = make_float4(s33[0], s33[1], s33[2], s33[3]);
            *(float4*)(slab + 5 * NPIX + pix) = make_float4(s44[0], s44[1], s44[2], s44[3]);
        }
    }
}

__global__ void ComputeTotalSim_finalize(const float* __restrict__ ws,
                                         float* __restrict__ out) {
    const int i = blockIdx.x * blockDim.x + threadIdx.x;
    if (i < NPIX) {
        double a0 = 0, a1 = 0, a2 = 0, a3 = 0, a4 = 0, a5 = 0;
#pragma unroll
        for (int cg = 0; cg < CGROUPS; ++cg) {
            const float* slab = ws + (size_t)cg * 6 * NPIX;
            a0 += slab[0 * NPIX + i];
            a1 += slab[1 * NPIX + i];
            a2 += slab[2 * NPIX + i];
            a3 += slab[3 * NPIX + i];
            a4 += slab[4 * NPIX + i];
            a5 += slab[5 * NPIX + i];
        }
        out[i] = (float)(0.5 * (a0 / sqrt(a1 * a2) + a3 / sqrt(a4 * a5)));
    }
}

extern "C" void kernel_launch(void* const* d_in, const int* in_sizes, int n_in,
                              void* d_out, int out_size, void* d_ws, size_t ws_size,
                              hipStream_t stream) {
    const float* feat = (const float*)d_in[0];
    float* out = (float*)d_out;

    const size_t need = (size_t)CGROUPS * 6 * NPIX * sizeof(float);  // 9.6 MB
    if (ws_size >= need) {
        // Phase 1: per-cgroup slab partials (plain stores, every slot written
        // every call -> no memset needed). Phase 2: sum slabs + cosine.
        dim3 grid(CGROUPS, HH / 4, BB);  // 8 x 14 x 16 = 1792 blocks
        ComputeTotalSim_84267258347855_kernel<CC / (4 * CGROUPS), false>
            <<<grid, 256, 0, stream>>>(feat, (float*)d_ws, out);
        ComputeTotalSim_finalize<<<(NPIX + 255) / 256, 256, 0, stream>>>(
            (const float*)d_ws, out);
    } else {
        // Fallback: single cgroup covers all 512 channels, writes out directly.
        dim3 grid(1, HH / 4, BB);
        ComputeTotalSim_84267258347855_kernel<CC / 4, true>
            <<<grid, 256, 0, stream>>>(feat, nullptr, out);
    }
}

// Round 9
// 34.104 us; speedup vs baseline: 1.4689x; 1.4689x over previous
//
#include <hip/hip_runtime.h>
#include <hip/hip_bf16.h>

// Problem constants: features [16, 512, 56, 56] f32, k=3 -> d=1
#define BB 16
#define CC 512
#define HH 56
#define WW 56
#define HW (HH * WW)
#define NPIX (BB * HW)   // 50176 output pixels
#define CGROUPS 8

typedef float v4f __attribute__((ext_vector_type(4)));

__device__ __forceinline__ float shfl64(float v, int srcLane) {
    return __shfl(v, srcLane, 64);
}

// Proven math (rounds 1/2/5/6/7, absmax <= 2e-3 < 9e-3); masks & 1/9 cancel:
//   V  = mym*g(y-1) + g(y) + myp*g(y+1)
//   w3 = mym*g(y)   + g(cl(y+1)) + myp*g(cl(y+2))
//   w4 = mym*g(cl(y-2)) + g(cl(y-1)) + myp*g(y)
//   f1(x) = mxm*V(cl(x-2)) + V(cl(x-1)) + mxp*V(x)
//   f2(x) = mxm*V(x) + V(cl(x+1)) + mxp*V(cl(x+2))
//   f3(x) = mxm*w3(cl(x-1)) + w3(x) + mxp*w3(cl(x+1))
//   f4(x) = mxm*w4(cl(x-1)) + w4(x) + mxp*w4(cl(x+1))
// Wave = one row y. lane = sc*16 + q: sc = channel sub-group (4 ch/iter),
// q = x-quad (float4/thread, q<14 active).
// R9 changes: STEP fully scalarized (R7's little arrays went to SCRATCH —
// WRITE_SIZE 9.4->44MB — whose buffer ops corrupted R8's counted vmcnt -> NaN).
// Interior strips: inline-asm dwordx4 loads + vmcnt(5)-counted double buffer.
template <int NITER, bool WRITE_OUT>
__global__ __launch_bounds__(256, 4) void ComputeTotalSim_84267258347855_kernel(
    const float* __restrict__ feat, float* __restrict__ ws, float* __restrict__ out) {
    const int wave = threadIdx.x >> 6;
    const int lane = threadIdx.x & 63;
    const int sc = lane >> 4;
    const int q = lane & 15;
    const int qs = (q <= 13) ? q : 13;  // idle lanes load safe real data
    const int x0 = 4 * qs;
    const int b = blockIdx.z;
    const int cg = blockIdx.x;
    const int y = blockIdx.y * 4 + wave;

    const float mym = (y >= 1) ? 1.f : 0.f;
    const float myp = (y <= HH - 2) ? 1.f : 0.f;
    const float mxm0 = (q == 0) ? 0.f : 1.f;   // applies only at j=0
    const float mxp3 = (q >= 13) ? 0.f : 1.f;  // applies only at j=3

    const int ry0 = (y - 2 < 0) ? 0 : y - 2;
    const int ry1 = (y - 1 < 0) ? 0 : y - 1;
    const int ry3 = (y + 1 > HH - 1) ? HH - 1 : y + 1;
    const int ry4 = (y + 2 > HH - 1) ? HH - 1 : y + 2;
    const int o0 = ry0 * WW + x0, o1 = ry1 * WW + x0, o2 = y * WW + x0,
              o3 = ry3 * WW + x0, o4 = ry4 * WW + x0;

    // channels: cg*(4*NITER) + 4*k + sc, k = 0..NITER-1
    const float* p = feat + ((size_t)b * CC + (size_t)cg * (4 * NITER) + sc) * HW;

    // 24 named accumulators (NO arrays anywhere -> no scratch possible)
    float sA0 = 0, sA1 = 0, sA2 = 0, sA3 = 0;  // s12h
    float sB0 = 0, sB1 = 0, sB2 = 0, sB3 = 0;  // s11
    float sC0 = 0, sC1 = 0, sC2 = 0, sC3 = 0;  // s22
    float sD0 = 0, sD1 = 0, sD2 = 0, sD3 = 0;  // s12v
    float sE0 = 0, sE1 = 0, sE2 = 0, sE3 = 0;  // s33
    float sF0 = 0, sF1 = 0, sF2 = 0, sF3 = 0;  // s44

#define STEP(A0, A1, A2, A3, A4)                                                \
    {                                                                           \
        const float Vx = fmaf(mym, A1.x, fmaf(myp, A3.x, A2.x));                \
        const float Vy = fmaf(mym, A1.y, fmaf(myp, A3.y, A2.y));                \
        const float Vz = fmaf(mym, A1.z, fmaf(myp, A3.z, A2.z));                \
        const float Vw = fmaf(mym, A1.w, fmaf(myp, A3.w, A2.w));                \
        const float t3x = fmaf(mym, A2.x, fmaf(myp, A4.x, A3.x));               \
        const float t3y = fmaf(mym, A2.y, fmaf(myp, A4.y, A3.y));               \
        const float t3z = fmaf(mym, A2.z, fmaf(myp, A4.z, A3.z));               \
        const float t3w = fmaf(mym, A2.w, fmaf(myp, A4.w, A3.w));               \
        const float t4x = fmaf(mym, A0.x, fmaf(myp, A2.x, A1.x));               \
        const float t4y = fmaf(mym, A0.y, fmaf(myp, A2.y, A1.y));               \
        const float t4z = fmaf(mym, A0.z, fmaf(myp, A2.z, A1.z));               \
        const float t4w = fmaf(mym, A0.w, fmaf(myp, A2.w, A1.w));               \
        float Vm2 = shfl64(Vz, lane - 1), Vm1 = shfl64(Vw, lane - 1);           \
        float Vp4 = shfl64(Vx, lane + 1), Vp5 = shfl64(Vy, lane + 1);           \
        float w3m = shfl64(t3w, lane - 1), w3p = shfl64(t3x, lane + 1);         \
        float w4m = shfl64(t4w, lane - 1), w4p = shfl64(t4x, lane + 1);         \
        if (q == 0) { Vm2 = Vx; Vm1 = Vx; w3m = t3x; w4m = t4x; }               \
        if (q >= 13) { Vp4 = Vw; Vp5 = Vw; w3p = t3w; w4p = t4w; }              \
        const float f10 = fmaf(mxm0, Vm2, Vm1 + Vx);                            \
        const float f11 = Vm1 + Vx + Vy;                                        \
        const float f12 = Vx + Vy + Vz;                                         \
        const float f13 = fmaf(mxp3, Vw, Vy + Vz);                              \
        const float f20 = fmaf(mxm0, Vx, Vy + Vz);                              \
        const float f21 = Vy + Vz + Vw;                                         \
        const float f22 = Vz + Vw + Vp4;                                        \
        const float f23 = fmaf(mxp3, Vp5, Vw + Vp4);                            \
        const float f30 = fmaf(mxm0, w3m, t3x + t3y);                           \
        const float f31 = t3x + t3y + t3z;                                      \
        const float f32 = t3y + t3z + t3w;                                      \
        const float f33 = fmaf(mxp3, w3p, t3z + t3w);                           \
        const float f40 = fmaf(mxm0, w4m, t4x + t4y);                           \
        const float f41 = t4x + t4y + t4z;                                      \
        const float f42 = t4y + t4z + t4w;                                      \
        const float f43 = fmaf(mxp3, w4p, t4z + t4w);                           \
        sA0 = fmaf(f10, f20, sA0); sA1 = fmaf(f11, f21, sA1);                   \
        sA2 = fmaf(f12, f22, sA2); sA3 = fmaf(f13, f23, sA3);                   \
        sB0 = fmaf(f10, f10, sB0); sB1 = fmaf(f11, f11, sB1);                   \
        sB2 = fmaf(f12, f12, sB2); sB3 = fmaf(f13, f13, sB3);                   \
        sC0 = fmaf(f20, f20, sC0); sC1 = fmaf(f21, f21, sC1);                   \
        sC2 = fmaf(f22, f22, sC2); sC3 = fmaf(f23, f23, sC3);                   \
        sD0 = fmaf(f30, f40, sD0); sD1 = fmaf(f31, f41, sD1);                   \
        sD2 = fmaf(f32, f42, sD2); sD3 = fmaf(f33, f43, sD3);                   \
        sE0 = fmaf(f30, f30, sE0); sE1 = fmaf(f31, f31, sE1);                   \
        sE2 = fmaf(f32, f32, sE2); sE3 = fmaf(f33, f33, sE3);                   \
        sF0 = fmaf(f40, f40, sF0); sF1 = fmaf(f41, f41, sF1);                   \
        sF2 = fmaf(f42, f42, sF2); sF3 = fmaf(f43, f43, sF3);                   \
    }

#define LOAD5(R0, R1, R2, R3, R4, PC)                                                      \
    asm volatile("global_load_dwordx4 %0, %1, off offset:-448" : "=&v"(R0) : "v"(PC));     \
    asm volatile("global_load_dwordx4 %0, %1, off offset:-224" : "=&v"(R1) : "v"(PC));     \
    asm volatile("global_load_dwordx4 %0, %1, off"             : "=&v"(R2) : "v"(PC));     \
    asm volatile("global_load_dwordx4 %0, %1, off offset:224"  : "=&v"(R3) : "v"(PC));     \
    asm volatile("global_load_dwordx4 %0, %1, off offset:448"  : "=&v"(R4) : "v"(PC));

#define WAITV(N)                                          \
    asm volatile("s_waitcnt vmcnt(" #N ")" ::: "memory"); \
    __builtin_amdgcn_sched_barrier(0);

    v4f A0, A1, A2, A3, A4, B0, B1, B2, B3, B4;

    if (blockIdx.y >= 1 && blockIdx.y <= 12) {
        // ---- interior strips: rows y-2..y+2 are exactly -448..+448 bytes ----
        const float* pc = p + o2;  // center-row per-lane address
        LOAD5(A0, A1, A2, A3, A4, pc); pc += 4 * HW;
        LOAD5(B0, B1, B2, B3, B4, pc); pc += 4 * HW;
        for (int k = 0; k + 4 <= NITER; k += 2) {
            WAITV(5);                                    // A ready, B in flight
            STEP(A0, A1, A2, A3, A4);
            LOAD5(A0, A1, A2, A3, A4, pc); pc += 4 * HW;
            WAITV(5);                                    // B ready, A' in flight
            STEP(B0, B1, B2, B3, B4);
            LOAD5(B0, B1, B2, B3, B4, pc); pc += 4 * HW;
        }
        WAITV(5);
        STEP(A0, A1, A2, A3, A4);
        WAITV(0);
        STEP(B0, B1, B2, B3, B4);
    } else {
        // ---- boundary strips (y-clamps active): proven C path ----
        A0 = *(const v4f*)(p + o0); A1 = *(const v4f*)(p + o1);
        A2 = *(const v4f*)(p + o2); A3 = *(const v4f*)(p + o3);
        A4 = *(const v4f*)(p + o4);
        p += 4 * HW;
        for (int k = 0; k + 2 <= NITER; k += 2) {
            B0 = *(const v4f*)(p + o0); B1 = *(const v4f*)(p + o1);
            B2 = *(const v4f*)(p + o2); B3 = *(const v4f*)(p + o3);
            B4 = *(const v4f*)(p + o4);
            STEP(A0, A1, A2, A3, A4);
            const float* pn = (k + 2 < NITER) ? p + 4 * HW : p;
            A0 = *(const v4f*)(pn + o0); A1 = *(const v4f*)(pn + o1);
            A2 = *(const v4f*)(pn + o2); A3 = *(const v4f*)(pn + o3);
            A4 = *(const v4f*)(pn + o4);
            STEP(B0, B1, B2, B3, B4);
            p = pn + 4 * HW;
        }
    }
#undef STEP
#undef LOAD5
#undef WAITV

    // ---- reduce across the 4 channel sub-groups (lanes q, q+16, q+32, q+48) ----
#define RED2(v) { v += __shfl_xor(v, 16, 64); v += __shfl_xor(v, 32, 64); }
    RED2(sA0) RED2(sA1) RED2(sA2) RED2(sA3)
    RED2(sB0) RED2(sB1) RED2(sB2) RED2(sB3)
    RED2(sC0) RED2(sC1) RED2(sC2) RED2(sC3)
    RED2(sD0) RED2(sD1) RED2(sD2) RED2(sD3)
    RED2(sE0) RED2(sE1) RED2(sE2) RED2(sE3)
    RED2(sF0) RED2(sF1) RED2(sF2) RED2(sF3)
#undef RED2

    if (lane < 14) {  // sc==0, q<14
        const int pix = b * HW + y * WW + 4 * q;
        if (WRITE_OUT) {
            v4f r;
            r.x = (float)(0.5 * ((double)sA0 / sqrt((double)sB0 * (double)sC0) +
                                 (double)sD0 / sqrt((double)sE0 * (double)sF0)));
            r.y = (float)(0.5 * ((double)sA1 / sqrt((double)sB1 * (double)sC1) +
                                 (double)sD1 / sqrt((double)sE1 * (double)sF1)));
            r.z = (float)(0.5 * ((double)sA2 / sqrt((double)sB2 * (double)sC2) +
                                 (double)sD2 / sqrt((double)sE2 * (double)sF2)));
            r.w = (float)(0.5 * ((double)sA3 / sqrt((double)sB3 * (double)sC3) +
                                 (double)sD3 / sqrt((double)sE3 * (double)sF3)));
            *(v4f*)(out + pix) = r;
        } else {
            float* slab = ws + (size_t)cg * 6 * NPIX;
            *(v4f*)(slab + 0 * NPIX + pix) = (v4f){sA0, sA1, sA2, sA3};
            *(v4f*)(slab + 1 * NPIX + pix) = (v4f){sB0, sB1, sB2, sB3};
            *(v4f*)(slab + 2 * NPIX + pix) = (v4f){sC0, sC1, sC2, sC3};
            *(v4f*)(slab + 3 * NPIX + pix) = (v4f){sD0, sD1, sD2, sD3};
            *(v4f*)(slab + 4 * NPIX + pix) = (v4f){sE0, sE1, sE2, sE3};
            *(v4f*)(slab + 5 * NPIX + pix) = (v4f){sF0, sF1, sF2, sF3};
        }
    }
}

__global__ void ComputeTotalSim_finalize(const float* __restrict__ ws,
                                         float* __restrict__ out) {
    const int i = blockIdx.x * blockDim.x + threadIdx.x;
    if (i < NPIX) {
        double a0 = 0, a1 = 0, a2 = 0, a3 = 0, a4 = 0, a5 = 0;
#pragma unroll
        for (int cg = 0; cg < CGROUPS; ++cg) {
            const float* slab = ws + (size_t)cg * 6 * NPIX;
            a0 += slab[0 * NPIX + i];
            a1 += slab[1 * NPIX + i];
            a2 += slab[2 * NPIX + i];
            a3 += slab[3 * NPIX + i];
            a4 += slab[4 * NPIX + i];
            a5 += slab[5 * NPIX + i];
        }
        out[i] = (float)(0.5 * (a0 / sqrt(a1 * a2) + a3 / sqrt(a4 * a5)));
    }
}

extern "C" void kernel_launch(void* const* d_in, const int* in_sizes, int n_in,
                              void* d_out, int out_size, void* d_ws, size_t ws_size,
                              hipStream_t stream) {
    const float* feat = (const float*)d_in[0];
    float* out = (float*)d_out;

    const size_t need = (size_t)CGROUPS * 6 * NPIX * sizeof(float);  // 9.6 MB
    if (ws_size >= need) {
        // Phase 1: per-cgroup slab partials (plain stores, every slot written
        // every call -> no memset needed). Phase 2: sum slabs + cosine.
        dim3 grid(CGROUPS, HH / 4, BB);  // 8 x 14 x 16 = 1792 blocks
        ComputeTotalSim_84267258347855_kernel<CC / (4 * CGROUPS), false>
            <<<grid, 256, 0, stream>>>(feat, (float*)d_ws, out);
        ComputeTotalSim_finalize<<<(NPIX + 255) / 256, 256, 0, stream>>>(
            (const float*)d_ws, out);
    } else {
        // Fallback: single cgroup covers all 512 channels, writes out directly.
        dim3 grid(1, HH / 4, BB);
        ComputeTotalSim_84267258347855_kernel<CC / 4, true>
            <<<grid, 256, 0, stream>>>(feat, nullptr, out);
    }
}